// Round 10
// baseline (495.766 us; speedup 1.0000x reference)
//
#include <hip/hip_runtime.h>

// Stable stream compaction: y[:count] = x[x>0] in original order, y[count:n]=0,
// y[out_size-1] = (float)count.
//
// 2 kernels (R10): count -> scatter-with-inline-scan.
//  - Single-pass lookback abandoned (R1=1956us PRE chain, R4=995us flat AGG,
//    R5=1575us hierarchical spin hotspot vs ~180us here): cross-XCD atomic
//    visibility latency makes inter-block WAITING structurally bad on MI355X.
//  - Slot staging abandoned (R8=516us): written lines don't survive in L3.
//  - L3 steering beyond R7 falsified (R3 neutral, R9 neutral-worse).
//  - R10 folds k_scan into k_scatter: each block computes its own exclusive
//    prefix by summing blockSums[0..chunk) directly (coalesced strided loads,
//    <=64/thread, 64 KB array hot in every XCD L2; NO waiting — data is final
//    at kernel boundary). Kills the k_scan dispatch + one launch gap.
//
//   k_count   : per-block positive count, coalesced float4 loads (forward:
//               leaves x resident in L3 tail for the reverse-order re-read)
//   k_scatter : REVERSE chunk order (L3 reuse, R7: measured win), inline
//               distributed scan, LDS-staged pad-aligned nt float4 stores,
//               fused nt zerofill of [count, n).

#define BLOCK 256
#define VPT 16               // elems per thread (contiguous, scatter only)
#define CHUNK (BLOCK * VPT)  // 4096

typedef float floatx4 __attribute__((ext_vector_type(4)));

__global__ void __launch_bounds__(BLOCK)
k_count(const float* __restrict__ x, int n, int* __restrict__ blockSums) {
    const int tid = threadIdx.x;
    const long long chunkBase = (long long)blockIdx.x * CHUNK;
    int cnt = 0;
    if (chunkBase + CHUNK <= n) {
        // coalesced: lane-contiguous float4, 4 rounds of 1024 elems
        const float* p = x + chunkBase + tid * 4;
#pragma unroll
        for (int it = 0; it < 4; ++it) {
            const float4 v = *reinterpret_cast<const float4*>(p + it * (BLOCK * 4));
            cnt += (v.x > 0.f) + (v.y > 0.f) + (v.z > 0.f) + (v.w > 0.f);
        }
    } else {
        const long long lim = (chunkBase + CHUNK < n) ? chunkBase + CHUNK : n;
        for (long long j = chunkBase + tid; j < lim; j += BLOCK) cnt += (x[j] > 0.f);
    }
#pragma unroll
    for (int off = 32; off > 0; off >>= 1) cnt += __shfl_down(cnt, off, 64);
    __shared__ int lds[4];
    if ((tid & 63) == 0) lds[tid >> 6] = cnt;
    __syncthreads();
    if (tid == 0) blockSums[blockIdx.x] = lds[0] + lds[1] + lds[2] + lds[3];
}

// exclusive block scan over 256 threads (4 waves); returns exclusive rank,
// sets *blockTotal. lds must have >= 9 ints.
__device__ __forceinline__ int block_scan_excl_256(int val, int* lds, int* blockTotal) {
    const int tid  = threadIdx.x;
    const int lane = tid & 63;
    const int wave = tid >> 6;
    int incl = val;
#pragma unroll
    for (int off = 1; off < 64; off <<= 1) {
        const int y = __shfl_up(incl, off, 64);
        if (lane >= off) incl += y;
    }
    if (lane == 63) lds[wave] = incl;
    __syncthreads();
    if (tid == 0) {
        const int s0 = lds[0], s1 = lds[1], s2 = lds[2], s3 = lds[3];
        lds[4] = 0; lds[5] = s0; lds[6] = s0 + s1; lds[7] = s0 + s1 + s2;
        lds[8] = s0 + s1 + s2 + s3;
    }
    __syncthreads();
    const int ex = lds[4 + wave] + incl - val;
    *blockTotal = lds[8];
    return ex;
}

__global__ void __launch_bounds__(BLOCK)
k_scatter(const float* __restrict__ x, int n, int numBlocks, int out_size,
          const int* __restrict__ blockSums, float* __restrict__ y) {
    __shared__ __align__(16) float vals[CHUNK + 4];  // +pad (up to 3) for aligned output
    __shared__ int scan_lds[9];
    __shared__ int red_lds[4];
    const int tid  = threadIdx.x;
    const int lane = tid & 63;
    const int wave = tid >> 6;
    const int chunk = numBlocks - 1 - blockIdx.x;    // reverse order for L3 reuse
    const int chunkBase = chunk * CHUNK;
    const long long tbase = (long long)chunkBase + tid * VPT;

    // x loads first (independent of the scan below; scheduler overlaps them).
    float v[VPT];
    if ((long long)chunkBase + CHUNK <= n) {
#pragma unroll
        for (int k = 0; k < 4; ++k) {
            const float4 f = *reinterpret_cast<const float4*>(x + tbase + 4 * k);
            v[4 * k + 0] = f.x; v[4 * k + 1] = f.y; v[4 * k + 2] = f.z; v[4 * k + 3] = f.w;
        }
    } else {
#pragma unroll
        for (int j = 0; j < VPT; ++j)
            v[j] = (tbase + j < n) ? x[tbase + j] : 0.f;
    }

    // Inline distributed scan: excl = sum(blockSums[0..chunk)).
    // Coalesced strided loads (<=64/thread); 64 KB array is L2-hot in every
    // XCD after first touch. No waiting — data finalized at kernel boundary.
    int psum = 0;
    for (int i = tid; i < chunk; i += BLOCK) psum += blockSums[i];
#pragma unroll
    for (int off = 32; off > 0; off >>= 1) psum += __shfl_down(psum, off, 64);
    if (lane == 0) red_lds[wave] = psum;

    int c = 0;
#pragma unroll
    for (int j = 0; j < VPT; ++j) c += (v[j] > 0.f);

    int total;
    int r = block_scan_excl_256(c, scan_lds, &total);  // has __syncthreads inside
    const int excl = red_lds[0] + red_lds[1] + red_lds[2] + red_lds[3];

    const int pad = excl & 3;                 // stage shifted so output is 16B-aligned
    r += pad;
#pragma unroll
    for (int j = 0; j < VPT; ++j) {
        if (v[j] > 0.f) vals[r++] = v[j];
    }
    __syncthreads();

    // Vectorized NONTEMPORAL store of positives: vals[k] <-> y[yb + k],
    // yb = excl - pad (mod 4 == 0). nt: don't allocate y lines in LLC.
    const int m = pad + total;
    const long long yb = (long long)excl - pad;
    const int nq = (m + 3) >> 2;
    for (int t = tid; t < nq; t += BLOCK) {
        const int k0 = 4 * t;
        if (k0 >= pad && k0 + 4 <= m) {
            __builtin_nontemporal_store(
                *reinterpret_cast<const floatx4*>(&vals[k0]),
                reinterpret_cast<floatx4*>(y + yb + k0));
        } else {
            const int ks = (k0 < pad) ? pad : k0;
            const int ke = (k0 + 4 < m) ? k0 + 4 : m;
            for (int k = ks; k < ke; ++k)
                __builtin_nontemporal_store(vals[k], y + yb + k);
        }
    }

    // Fused zerofill (nontemporal): this block's zeros tile a slice of
    // [count, n) from the top down; regions are disjoint and cover it exactly.
    const int rem   = n - chunkBase;
    const int elems = rem < CHUNK ? rem : CHUNK;
    const int z     = elems - total;
    const long long zhi = (long long)n - (chunkBase - excl);
    const long long zlo = zhi - z;
    const long long za  = (zlo + 3) & ~3LL;    // first aligned quad start
    const long long zb  = zhi & ~3LL;          // last aligned quad end
    if (za >= zb) {
        for (long long j = zlo + tid; j < zhi; j += BLOCK)
            __builtin_nontemporal_store(0.f, y + j);
    } else {
        if (tid < (int)(za - zlo))
            __builtin_nontemporal_store(0.f, y + zlo + tid);               // head (<=3)
        if (tid >= 4 && tid - 4 < (int)(zhi - zb))
            __builtin_nontemporal_store(0.f, y + zb + tid - 4);            // tail (<=3)
        const int zq = (int)((zb - za) >> 2);
        const floatx4 zero = (floatx4)(0.f);
        for (int t = tid; t < zq; t += BLOCK) {
            __builtin_nontemporal_store(zero, reinterpret_cast<floatx4*>(y + za + 4 * t));
        }
    }

    if (chunk == numBlocks - 1 && tid == 0) {
        y[out_size - 1] = (float)(excl + total);
    }
}

extern "C" void kernel_launch(void* const* d_in, const int* in_sizes, int n_in,
                              void* d_out, int out_size, void* d_ws, size_t ws_size,
                              hipStream_t stream) {
    const float* x = (const float*)d_in[0];
    float* y = (float*)d_out;
    const int n = in_sizes[0];

    int* blockSums = (int*)d_ws;
    const int numBlocks = (n + CHUNK - 1) / CHUNK;   // 16384 for N=64M

    k_count<<<numBlocks, BLOCK, 0, stream>>>(x, n, blockSums);
    k_scatter<<<numBlocks, BLOCK, 0, stream>>>(x, n, numBlocks, out_size, blockSums, y);
}

// Round 11
// 479.111 us; speedup vs baseline: 1.0348x; 1.0348x over previous
//
#include <hip/hip_runtime.h>

// Stable stream compaction: y[:count] = x[x>0] in original order, y[count:n]=0,
// y[out_size-1] = (float)count.
//
// BEST MEASURED (R7 = 481.6us). Restored after R8/R9/R10 regressions.
//
// reduce-then-scan, 3 kernels. Measured-out dead ends:
//  - single-pass lookback: R1=1956us (PRE chain), R4=995us (flat AGG,
//    134M flag loads), R5=1575us (hierarchical, spin hotspot) — cross-XCD
//    atomic visibility latency makes inter-block waiting structurally bad.
//  - slot staging (R8=516us): staged lines don't survive L3 vs y stream.
//  - fractional nt-residency (R9=489us), inline distributed scan (R10=496us).
//
//   k_count   : per-block positive count, coalesced float4 loads (forward:
//               populates L3 with x)
//   k_scan    : single-block exclusive scan of 16384 block sums + count out
//   k_scatter : REVERSE chunk order (re-read meets L3 residue) + ALL y stores
//               NONTEMPORAL (don't evict x) + LDS-staged pad-aligned float4
//               stores + fused nt zerofill of [count, n).

#define BLOCK 256
#define VPT 16               // elems per thread (contiguous, scatter only)
#define CHUNK (BLOCK * VPT)  // 4096
#define SCAN_THREADS 1024
#define SCAN_VPT 16          // scan supports up to 16384 block sums

typedef float floatx4 __attribute__((ext_vector_type(4)));

__global__ void __launch_bounds__(BLOCK)
k_count(const float* __restrict__ x, int n, int* __restrict__ blockSums) {
    const int tid = threadIdx.x;
    const long long chunkBase = (long long)blockIdx.x * CHUNK;
    int cnt = 0;
    if (chunkBase + CHUNK <= n) {
        // coalesced: lane-contiguous float4, 4 rounds of 1024 elems
        const float* p = x + chunkBase + tid * 4;
#pragma unroll
        for (int it = 0; it < 4; ++it) {
            const float4 v = *reinterpret_cast<const float4*>(p + it * (BLOCK * 4));
            cnt += (v.x > 0.f) + (v.y > 0.f) + (v.z > 0.f) + (v.w > 0.f);
        }
    } else {
        const long long lim = (chunkBase + CHUNK < n) ? chunkBase + CHUNK : n;
        for (long long j = chunkBase + tid; j < lim; j += BLOCK) cnt += (x[j] > 0.f);
    }
#pragma unroll
    for (int off = 32; off > 0; off >>= 1) cnt += __shfl_down(cnt, off, 64);
    __shared__ int lds[4];
    if ((tid & 63) == 0) lds[tid >> 6] = cnt;
    __syncthreads();
    if (tid == 0) blockSums[blockIdx.x] = lds[0] + lds[1] + lds[2] + lds[3];
}

// Single-block exclusive scan of blockSums (numBlocks <= SCAN_THREADS*SCAN_VPT).
__global__ void k_scan(int* __restrict__ sums, int numBlocks,
                       int* __restrict__ countOut, float* __restrict__ countOutF) {
    __shared__ int lds[32];
    const int tid  = threadIdx.x;
    const int lane = tid & 63;
    const int wave = tid >> 6;   // 16 waves

    int vals[SCAN_VPT];
    const int base = tid * SCAN_VPT;
    int local = 0;
#pragma unroll
    for (int j = 0; j < SCAN_VPT; ++j) {
        const int i = base + j;
        const int v = (i < numBlocks) ? sums[i] : 0;
        vals[j] = local;         // thread-local exclusive
        local += v;
    }
    int incl = local;
#pragma unroll
    for (int off = 1; off < 64; off <<= 1) {
        const int y = __shfl_up(incl, off, 64);
        if (lane >= off) incl += y;
    }
    if (lane == 63) lds[wave] = incl;
    __syncthreads();
    if (wave == 0 && lane < 16) {
        int w = lds[lane];
#pragma unroll
        for (int off = 1; off < 16; off <<= 1) {
            const int y = __shfl_up(w, off, 16);
            if ((lane & 15) >= off) w += y;
        }
        lds[16 + lane] = w;      // inclusive wave prefix
    }
    __syncthreads();
    const int waveEx   = (wave == 0) ? 0 : lds[16 + wave - 1];
    const int threadEx = waveEx + incl - local;
#pragma unroll
    for (int j = 0; j < SCAN_VPT; ++j) {
        const int i = base + j;
        if (i < numBlocks) sums[i] = threadEx + vals[j];
    }
    if (tid == SCAN_THREADS - 1) {
        const int total = waveEx + incl;
        *countOut  = total;
        *countOutF = (float)total;
    }
}

// exclusive block scan over 256 threads (4 waves); returns exclusive rank,
// sets *blockTotal. lds must have >= 9 ints.
__device__ __forceinline__ int block_scan_excl_256(int val, int* lds, int* blockTotal) {
    const int tid  = threadIdx.x;
    const int lane = tid & 63;
    const int wave = tid >> 6;
    int incl = val;
#pragma unroll
    for (int off = 1; off < 64; off <<= 1) {
        const int y = __shfl_up(incl, off, 64);
        if (lane >= off) incl += y;
    }
    if (lane == 63) lds[wave] = incl;
    __syncthreads();
    if (tid == 0) {
        const int s0 = lds[0], s1 = lds[1], s2 = lds[2], s3 = lds[3];
        lds[4] = 0; lds[5] = s0; lds[6] = s0 + s1; lds[7] = s0 + s1 + s2;
        lds[8] = s0 + s1 + s2 + s3;
    }
    __syncthreads();
    const int ex = lds[4 + wave] + incl - val;
    *blockTotal = lds[8];
    return ex;
}

__global__ void __launch_bounds__(BLOCK)
k_scatter(const float* __restrict__ x, int n, int numBlocks,
          const int* __restrict__ blockOffsets, float* __restrict__ y) {
    __shared__ __align__(16) float vals[CHUNK + 4];  // +pad (up to 3) for aligned output
    __shared__ int scan_lds[9];
    const int tid = threadIdx.x;
    const int chunk = numBlocks - 1 - blockIdx.x;    // reverse order for L3 reuse
    const int chunkBase = chunk * CHUNK;
    const long long tbase = (long long)chunkBase + tid * VPT;

    float v[VPT];
    if ((long long)chunkBase + CHUNK <= n) {
#pragma unroll
        for (int k = 0; k < 4; ++k) {
            const float4 f = *reinterpret_cast<const float4*>(x + tbase + 4 * k);
            v[4 * k + 0] = f.x; v[4 * k + 1] = f.y; v[4 * k + 2] = f.z; v[4 * k + 3] = f.w;
        }
    } else {
#pragma unroll
        for (int j = 0; j < VPT; ++j)
            v[j] = (tbase + j < n) ? x[tbase + j] : 0.f;
    }

    int c = 0;
#pragma unroll
    for (int j = 0; j < VPT; ++j) c += (v[j] > 0.f);

    int total;
    int r = block_scan_excl_256(c, scan_lds, &total);

    const int excl = blockOffsets[chunk];
    const int pad  = excl & 3;                 // stage shifted so output is 16B-aligned

    r += pad;
#pragma unroll
    for (int j = 0; j < VPT; ++j) {
        if (v[j] > 0.f) vals[r++] = v[j];
    }
    __syncthreads();

    // Vectorized NONTEMPORAL store of positives: vals[k] <-> y[yb + k],
    // yb = excl - pad (mod 4 == 0). nt: don't allocate y lines in LLC.
    const int m = pad + total;
    const long long yb = (long long)excl - pad;
    const int nq = (m + 3) >> 2;
    for (int t = tid; t < nq; t += BLOCK) {
        const int k0 = 4 * t;
        if (k0 >= pad && k0 + 4 <= m) {
            __builtin_nontemporal_store(
                *reinterpret_cast<const floatx4*>(&vals[k0]),
                reinterpret_cast<floatx4*>(y + yb + k0));
        } else {
            const int ks = (k0 < pad) ? pad : k0;
            const int ke = (k0 + 4 < m) ? k0 + 4 : m;
            for (int k = ks; k < ke; ++k)
                __builtin_nontemporal_store(vals[k], y + yb + k);
        }
    }

    // Fused zerofill (nontemporal): this block's zeros tile a slice of
    // [count, n) from the top down; regions are disjoint and cover it exactly.
    const int rem   = n - chunkBase;
    const int elems = rem < CHUNK ? rem : CHUNK;
    const int z     = elems - total;
    const long long zhi = (long long)n - (chunkBase - excl);
    const long long zlo = zhi - z;
    const long long za  = (zlo + 3) & ~3LL;    // first aligned quad start
    const long long zb  = zhi & ~3LL;          // last aligned quad end
    if (za >= zb) {
        for (long long j = zlo + tid; j < zhi; j += BLOCK)
            __builtin_nontemporal_store(0.f, y + j);
    } else {
        if (tid < (int)(za - zlo))
            __builtin_nontemporal_store(0.f, y + zlo + tid);               // head (<=3)
        if (tid >= 4 && tid - 4 < (int)(zhi - zb))
            __builtin_nontemporal_store(0.f, y + zb + tid - 4);            // tail (<=3)
        const int zq = (int)((zb - za) >> 2);
        const floatx4 zero = (floatx4)(0.f);
        for (int t = tid; t < zq; t += BLOCK) {
            __builtin_nontemporal_store(zero, reinterpret_cast<floatx4*>(y + za + 4 * t));
        }
    }
}

extern "C" void kernel_launch(void* const* d_in, const int* in_sizes, int n_in,
                              void* d_out, int out_size, void* d_ws, size_t ws_size,
                              hipStream_t stream) {
    const float* x = (const float*)d_in[0];
    float* y = (float*)d_out;
    const int n = in_sizes[0];

    int* blockSums = (int*)d_ws;
    const int numBlocks = (n + CHUNK - 1) / CHUNK;   // 16384 for N=64M
    int* countPtr = blockSums + numBlocks;

    k_count<<<numBlocks, BLOCK, 0, stream>>>(x, n, blockSums);
    k_scan<<<1, SCAN_THREADS, 0, stream>>>(blockSums, numBlocks,
                                           countPtr, y + (out_size - 1));
    k_scatter<<<numBlocks, BLOCK, 0, stream>>>(x, n, numBlocks, blockSums, y);
}